// Round 5
// baseline (202.033 us; speedup 1.0000x reference)
//
#include <hip/hip_runtime.h>

#define KLEN 2048
#define SCH 8           // trellis steps per thread
#define TPR 256         // threads per row (4 waves)
#define NEGV (-1e4f)

typedef float v2f __attribute__((ext_vector_type(2)));

// ---- packed dual-FP32 helpers (VOP3P v_pk_add_f32) ----
static __device__ __forceinline__ v2f pka(v2f a, v2f b) {        // (a.x+b.x, a.y+b.y)
  v2f d; asm("v_pk_add_f32 %0, %1, %2" : "=v"(d) : "v"(a), "v"(b)); return d;
}
static __device__ __forceinline__ v2f pkabl(v2f a, v2f b) {      // (a.x+b.x, a.y+b.x)
  v2f d; asm("v_pk_add_f32 %0, %1, %2 op_sel:[0,0] op_sel_hi:[1,0]"
             : "=v"(d) : "v"(a), "v"(b)); return d;
}
static __device__ __forceinline__ v2f pkabh(v2f a, v2f b) {      // (a.x+b.y, a.y+b.y)
  v2f d; asm("v_pk_add_f32 %0, %1, %2 op_sel:[0,1] op_sel_hi:[1,1]"
             : "=v"(d) : "v"(a), "v"(b)); return d;
}
static __device__ __forceinline__ v2f pkasw(v2f a, v2f b) {      // (a.x+b.y, a.y+b.x)
  v2f d; asm("v_pk_add_f32 %0, %1, %2 op_sel:[0,1] op_sel_hi:[1,0]"
             : "=v"(d) : "v"(a), "v"(b)); return d;
}

struct SM {
  float y1[KLEN];             // systematic, natural order
  float y1i[KLEN];            // systematic, interleaved
  float Lint[KLEN];           // La for decoder 1 (natural)
  float A[KLEN];              // La for decoder 2 (interleaved); bits staging
  unsigned short perm[KLEN];
  unsigned short invp[KLEN];
  v2f fT[4][8];               // per-wave forward totals (col-pair layout)
  v2f bT[4][8];               // per-wave backward totals
  unsigned int eT[4][2];
};

// Matrix layout: X[2j] = {M[0][j], M[1][j]},  X[2j+1] = {M[2][j], M[3][j]}

template <int CTRL>
__device__ __forceinline__ v2f dpp2(v2f x) {
  int lo = __builtin_amdgcn_update_dpp(__float_as_int(x.x), __float_as_int(x.x),
                                       CTRL, 0xF, 0xF, false);
  int hi = __builtin_amdgcn_update_dpp(__float_as_int(x.y), __float_as_int(x.y),
                                       CTRL, 0xF, 0xF, false);
  v2f r; r.x = __int_as_float(lo); r.y = __int_as_float(hi); return r;
}

template <int CTRL>
__device__ __forceinline__ void shift8(const v2f (&X)[8], v2f (&T)[8]) {
#pragma unroll
  for (int e = 0; e < 8; ++e) T[e] = dpp2<CTRL>(X[e]);
}

__device__ __forceinline__ void cp8(v2f (&D)[8], const v2f (&S)[8]) {
#pragma unroll
  for (int e = 0; e < 8; ++e) D[e] = S[e];
}

// Z = X (later) (x) Y (earlier), max-plus, packed adds
__device__ __forceinline__ void comb(const v2f (&X)[8], const v2f (&Y)[8],
                                     v2f (&Z)[8]) {
#pragma unroll
  for (int j = 0; j < 4; ++j) {
    v2f y01 = Y[2 * j], y23 = Y[2 * j + 1];
    v2f a0 = pkabl(X[0], y01), b0 = pkabl(X[1], y01);   // k=0
    v2f a1 = pkabh(X[2], y01), b1 = pkabh(X[3], y01);   // k=1
    v2f a2 = pkabl(X[4], y23), b2 = pkabl(X[5], y23);   // k=2
    v2f a3 = pkabh(X[6], y23), b3 = pkabh(X[7], y23);   // k=3
    v2f z01, z23;
    z01.x = fmaxf(fmaxf(a0.x, a1.x), fmaxf(a2.x, a3.x));
    z01.y = fmaxf(fmaxf(a0.y, a1.y), fmaxf(a2.y, a3.y));
    z23.x = fmaxf(fmaxf(b0.x, b1.x), fmaxf(b2.x, b3.x));
    z23.y = fmaxf(fmaxf(b0.y, b1.y), fmaxf(b2.y, b3.y));
    Z[2 * j] = z01; Z[2 * j + 1] = z23;
  }
}

// chunk matrix over SCH steps, col-pair layout, normalized to max 0
__device__ __forceinline__ void buildM(const float (&p)[SCH], const float (&q)[SCH],
                                       v2f (&X)[8]) {
  {
    float ppq = p[0] + q[0], pmq = p[0] - q[0];
    X[0].x = -ppq; X[0].y = NEGV;  X[1].x =  ppq; X[1].y = NEGV;   // col0
    X[2].x =  ppq; X[2].y = NEGV;  X[3].x = -ppq; X[3].y = NEGV;   // col1
    X[4].x = NEGV; X[4].y =  pmq;  X[5].x = NEGV; X[5].y = -pmq;   // col2
    X[6].x = NEGV; X[6].y = -pmq;  X[7].x = NEGV; X[7].y =  pmq;   // col3
  }
#pragma unroll
  for (int k = 1; k < SCH; ++k) {
    float ppq = p[k] + q[k], pmq = p[k] - q[k];
    v2f Wp; Wp.x = -ppq; Wp.y = ppq;
    v2f Wm; Wm.x = pmq;  Wm.y = -pmq;
#pragma unroll
    for (int j = 0; j < 4; ++j) {
      v2f c01 = X[2 * j], c23 = X[2 * j + 1];
      v2f t = pka(c01, Wp);    // (r0-ppq, r1+ppq) -> new0
      v2f u = pkasw(c01, Wp);  // (r0+ppq, r1-ppq) -> new2
      v2f v = pka(c23, Wm);    // (r2+pmq, r3-pmq) -> new1
      v2f s = pkasw(c23, Wm);  // (r2-pmq, r3+pmq) -> new3
      v2f n01, n23;
      n01.x = fmaxf(t.x, t.y); n01.y = fmaxf(v.x, v.y);
      n23.x = fmaxf(u.x, u.y); n23.y = fmaxf(s.x, s.y);
      X[2 * j] = n01; X[2 * j + 1] = n23;
    }
  }
  float mx = fmaxf(fmaxf(fmaxf(X[0].x, X[0].y), fmaxf(X[1].x, X[1].y)),
                   fmaxf(fmaxf(X[2].x, X[2].y), fmaxf(X[3].x, X[3].y)));
  mx = fmaxf(mx, fmaxf(fmaxf(fmaxf(X[4].x, X[4].y), fmaxf(X[5].x, X[5].y)),
                       fmaxf(fmaxf(X[6].x, X[6].y), fmaxf(X[7].x, X[7].y))));
  v2f mn; mn.x = -mx; mn.y = -mx;
#pragma unroll
  for (int e = 0; e < 8; ++e) X[e] = pka(X[e], mn);
}

// one BCJR pass: 256 threads (4 waves) x SCH steps, hierarchical scan, packed math
__device__ __forceinline__ void bcjr_pass(
    const float* ys, const float* La, float* dst, const unsigned short* widx,
    int finalLLR, const float (&q)[SCH], v2f (&fT)[4][8], v2f (&bT)[4][8],
    int c, int lane, int w) {
  const int base = c * SCH;
  float p[SCH];
  {
    const float4* y4 = (const float4*)(ys + base);
    const float4* l4 = (const float4*)(La + base);
#pragma unroll
    for (int k = 0; k < SCH / 4; ++k) {
      float4 yv = y4[k], lv = l4[k];
      p[4 * k + 0] = yv.x + 0.5f * lv.x;
      p[4 * k + 1] = yv.y + 0.5f * lv.y;
      p[4 * k + 2] = yv.z + 0.5f * lv.z;
      p[4 * k + 3] = yv.w + 0.5f * lv.w;
    }
  }

  v2f P[8];
  buildM(p, q, P);
  v2f Q[8];
  cp8(Q, P);

  const int rl = lane & 15;
  const int row = lane >> 4;

  // ---- intra-wave forward inclusive scan (DPP) ----
  {
    v2f T[8], N[8];
    shift8<0x111>(P, T); if (rl >= 1) { comb(P, T, N); cp8(P, N); }
    shift8<0x112>(P, T); if (rl >= 2) { comb(P, T, N); cp8(P, N); }
    shift8<0x114>(P, T); if (rl >= 4) { comb(P, T, N); cp8(P, N); }
    shift8<0x118>(P, T); if (rl >= 8) { comb(P, T, N); cp8(P, N); }
    shift8<0x142>(P, T); if (row & 1)  { comb(P, T, N); cp8(P, N); }  // bcast15
    shift8<0x143>(P, T); if (row >= 2) { comb(P, T, N); cp8(P, N); }  // bcast31
  }
  // ---- intra-wave backward (suffix) scan: DPP in-row + 2 shfl stitch levels ----
  {
    v2f T[8], N[8];
    shift8<0x101>(Q, T); if (rl <= 14) { comb(T, Q, N); cp8(Q, N); }
    shift8<0x102>(Q, T); if (rl <= 13) { comb(T, Q, N); cp8(Q, N); }
    shift8<0x104>(Q, T); if (rl <= 11) { comb(T, Q, N); cp8(Q, N); }
    shift8<0x108>(Q, T); if (rl <= 7)  { comb(T, Q, N); cp8(Q, N); }
#pragma unroll
    for (int d = 1; d <= 2; d <<= 1) {
      int src = (row + d) << 4;
      v2f T2[8];
#pragma unroll
      for (int e = 0; e < 8; ++e) {
        T2[e].x = __shfl(Q[e].x, src);
        T2[e].y = __shfl(Q[e].y, src);
      }
      if (row + d <= 3) { v2f N2[8]; comb(T2, Q, N2); cp8(Q, N2); }
    }
  }

  // ---- wave totals -> LDS ----
  if (lane == 63) cp8(fT[w], P);
  if (lane == 0)  cp8(bT[w], Q);
  __syncthreads();

  // ---- cross-wave apply ----
  v2f F[8];                    // product of forward totals of waves < w
  {
    v2f t[8], n[8];
    if (w >= 1) cp8(F, fT[0]);
    if (w >= 2) { cp8(t, fT[1]); comb(t, F, n); cp8(F, n); }
    if (w >= 3) { cp8(t, fT[2]); comb(t, F, n); cp8(F, n); }
    if (w >= 1) { comb(P, F, n); cp8(P, n); }
  }
  v2f Bm[8];                   // product of backward totals of waves > w
  {
    v2f t[8], n[8];
    if (w <= 2) cp8(Bm, bT[3]);
    if (w <= 1) { cp8(t, bT[2]); comb(Bm, t, n); cp8(Bm, n); }
    if (w <= 0) { cp8(t, bT[1]); comb(Bm, t, n); cp8(Bm, n); }
    if (w <= 2) { comb(Bm, Q, n); cp8(Q, n); }
  }

  // alpha at chunk start = col 0 of global prefix at c-1 (as deltas vs state 0)
  v2f A01, A23;                // {a0,a1}, {a2,a3}
  {
    float a0 = __shfl(P[0].x, lane - 1), a1 = __shfl(P[0].y, lane - 1);
    float a2 = __shfl(P[1].x, lane - 1), a3 = __shfl(P[1].y, lane - 1);
    if (c == 0) { A01.x = 0.f; A01.y = NEGV; A23.x = NEGV; A23.y = NEGV; }
    else {
      if (lane == 0) { a0 = F[0].x; a1 = F[0].y; a2 = F[1].x; a3 = F[1].y; }
      A01.x = 0.f; A01.y = a1 - a0; A23.x = a2 - a0; A23.y = a3 - a0;
    }
  }

  // beta at chunk end = col-max of global suffix at c+1
  v2f B02, B13;                // {b0,b2}, {b1,b3}
  {
    float m0 = fmaxf(fmaxf(Q[0].x, Q[0].y), fmaxf(Q[1].x, Q[1].y));
    float m1 = fmaxf(fmaxf(Q[2].x, Q[2].y), fmaxf(Q[3].x, Q[3].y));
    float m2 = fmaxf(fmaxf(Q[4].x, Q[4].y), fmaxf(Q[5].x, Q[5].y));
    float m3 = fmaxf(fmaxf(Q[6].x, Q[6].y), fmaxf(Q[7].x, Q[7].y));
    float b0 = __shfl(m0, lane + 1), b1 = __shfl(m1, lane + 1);
    float b2 = __shfl(m2, lane + 1), b3 = __shfl(m3, lane + 1);
    if (c == TPR - 1) { B02.x = 0.f; B02.y = 0.f; B13.x = 0.f; B13.y = 0.f; }
    else {
      if (lane == 63) {
        b0 = fmaxf(fmaxf(Bm[0].x, Bm[0].y), fmaxf(Bm[1].x, Bm[1].y));
        b1 = fmaxf(fmaxf(Bm[2].x, Bm[2].y), fmaxf(Bm[3].x, Bm[3].y));
        b2 = fmaxf(fmaxf(Bm[4].x, Bm[4].y), fmaxf(Bm[5].x, Bm[5].y));
        b3 = fmaxf(fmaxf(Bm[6].x, Bm[6].y), fmaxf(Bm[7].x, Bm[7].y));
      }
      B02.x = 0.f; B02.y = b2 - b0; B13.x = b1 - b0; B13.y = b3 - b0;
    }
  }

  // local beta walk: bet pairs {B0,B2},{B1,B3} for beta_{base+k+1}
  v2f bet02[SCH], bet13[SCH];
  bet02[SCH - 1] = B02; bet13[SCH - 1] = B13;
#pragma unroll
  for (int k = SCH - 1; k >= 1; --k) {
    float ppq = p[k] + q[k], pmq = p[k] - q[k];
    v2f Wp; Wp.x = -ppq; Wp.y = ppq;
    v2f Wm; Wm.x = pmq;  Wm.y = -pmq;
    v2f P02 = bet02[k], P13 = bet13[k];
    v2f t = pka(P02, Wp);     // (B0-ppq, B2+ppq) -> B0'
    v2f u = pkasw(P02, Wp);   // (B0+ppq, B2-ppq) -> B1'
    v2f v = pka(P13, Wm);     // (B1+pmq, B3-pmq) -> B2'
    v2f s = pkasw(P13, Wm);   // (B1-pmq, B3+pmq) -> B3'
    v2f n02, n13;
    n02.x = fmaxf(t.x, t.y);  n02.y = fmaxf(v.x, v.y);
    n13.x = fmaxf(u.x, u.y);  n13.y = fmaxf(s.x, s.y);
    bet02[k - 1] = n02; bet13[k - 1] = n13;
  }

  // alpha walk + LLR + scattered write (reuses packed butterfly terms)
#pragma unroll
  for (int k = 0; k < SCH; ++k) {
    float ppq = p[k] + q[k], pmq = p[k] - q[k];
    v2f Wp; Wp.x = -ppq; Wp.y = ppq;
    v2f Wm; Wm.x = pmq;  Wm.y = -pmq;
    v2f t = pka(A01, Wp);     // (a0-ppq, a1+ppq)
    v2f u = pkasw(A01, Wp);   // (a0+ppq, a1-ppq)
    v2f v = pka(A23, Wm);     // (a2+pmq, a3-pmq)
    v2f s = pkasw(A23, Wm);   // (a2-pmq, a3+pmq)
    float B0 = bet02[k].x, B2 = bet02[k].y, B1 = bet13[k].x, B3 = bet13[k].y;
    float m1 = fmaxf(fmaxf(t.y + B0, u.x + B2), fmaxf(v.x + B1, s.y + B3));
    float m0 = fmaxf(fmaxf(t.x + B0, u.y + B2), fmaxf(s.x + B3, v.y + B1));
    float llr = m1 - m0;
    float val = finalLLR ? llr : (llr - 2.f * p[k]);
    dst[widx[base + k]] = val;
    A01.x = fmaxf(t.x, t.y);  A01.y = fmaxf(v.x, v.y);
    A23.x = fmaxf(u.x, u.y);  A23.y = fmaxf(s.x, s.y);
  }
}

__device__ __forceinline__ unsigned fsm_compose(unsigned f, unsigned g) {
  unsigned nm = 0;
#pragma unroll
  for (int s = 0; s < 4; ++s) {
    unsigned gs = (g >> (8 * s)) & 3u;
    nm |= ((f >> (8 * gs)) & 0xFFu) << (8 * s);
  }
  return nm;
}

__global__ __launch_bounds__(TPR, 2) void turbo_kernel(
    const int* __restrict__ xg, const float* __restrict__ n1g,
    const float* __restrict__ n2g, const float* __restrict__ n3g,
    const int* __restrict__ pg, float* __restrict__ outg) {
  __shared__ SM sm;
  const int tid = threadIdx.x;
  const int c = tid, lane = tid & 63, w = tid >> 6;
  const size_t rb = (size_t)blockIdx.x * KLEN;

  // ---- load inputs ----
  int* Ai = (int*)sm.A;
  for (int i = tid; i < KLEN; i += TPR) {
    sm.perm[i] = (unsigned short)pg[i];
    int xv = xg[rb + i];
    Ai[i] = xv;
    sm.y1[i] = (2.f * xv - 1.f) + n1g[rb + i];
    sm.Lint[i] = 0.f;
  }
  float q2[SCH], q3[SCH];
  {
    size_t g0 = rb + (size_t)c * SCH;
#pragma unroll
    for (int k = 0; k < SCH; ++k) { q2[k] = n2g[g0 + k]; q3[k] = n3g[g0 + k]; }
  }
  __syncthreads();

  // ---- one-time: invp, interleaved systematic ----
  for (int i = tid; i < KLEN; i += TPR) {
    sm.invp[sm.perm[i]] = (unsigned short)i;
    sm.y1i[i] = sm.y1[sm.perm[i]];
  }

  // ---- RSC encode via FSM hierarchical scan ----
  unsigned ub1 = 0, ub2 = 0;
#pragma unroll
  for (int k = 0; k < SCH; ++k) {
    int t = c * SCH + k;
    ub1 |= (unsigned)(Ai[t] & 1) << k;
    ub2 |= (unsigned)(Ai[sm.perm[t]] & 1) << k;
  }
  unsigned m1 = 0x03020100u, m2 = 0x03020100u;
#pragma unroll
  for (int k = 0; k < SCH; ++k) {
    unsigned st1 = ((ub1 >> k) & 1) ? 0x03010002u : 0x01030200u;
    unsigned st2 = ((ub2 >> k) & 1) ? 0x03010002u : 0x01030200u;
    m1 = fsm_compose(st1, m1);
    m2 = fsm_compose(st2, m2);
  }
#pragma unroll
  for (int i = 0; i < 6; ++i) {
    const int d = 1 << i;
    unsigned t1 = __shfl_up(m1, d), t2 = __shfl_up(m2, d);
    if (lane >= d) { m1 = fsm_compose(m1, t1); m2 = fsm_compose(m2, t2); }
  }
  if (lane == 63) { sm.eT[w][0] = m1; sm.eT[w][1] = m2; }
  __syncthreads();
  {
    unsigned W1 = 0x03020100u, W2 = 0x03020100u;
    if (w >= 1) { W1 = sm.eT[0][0]; W2 = sm.eT[0][1]; }
    if (w >= 2) { W1 = fsm_compose(sm.eT[1][0], W1); W2 = fsm_compose(sm.eT[1][1], W2); }
    if (w >= 3) { W1 = fsm_compose(sm.eT[2][0], W1); W2 = fsm_compose(sm.eT[2][1], W2); }
    unsigned f1 = fsm_compose(m1, W1), f2 = fsm_compose(m2, W2);
    unsigned pf1 = __shfl_up(f1, 1), pf2 = __shfl_up(f2, 1);
    int s1 = (c == 0) ? 0 : (lane == 0 ? (int)(W1 & 3u) : (int)(pf1 & 3u));
    int s2 = (c == 0) ? 0 : (lane == 0 ? (int)(W2 & 3u) : (int)(pf2 & 3u));
#pragma unroll
    for (int k = 0; k < SCH; ++k) {
      { int u = (ub1 >> k) & 1, a = u ^ (s1 >> 1) ^ (s1 & 1), par = a ^ (s1 & 1);
        q2[k] += 2.f * par - 1.f; s1 = (a << 1) | (s1 >> 1); }
      { int u = (ub2 >> k) & 1, a = u ^ (s2 >> 1) ^ (s2 & 1), par = a ^ (s2 & 1);
        q3[k] += 2.f * par - 1.f; s2 = (a << 1) | (s2 >> 1); }
    }
  }
  __syncthreads();  // bits consumed; A becomes interleaved-La buffer

  // ---- 6 turbo iterations ----
#pragma unroll 1
  for (int it = 0; it < 6; ++it) {
    bcjr_pass(sm.y1, sm.Lint, sm.A, sm.invp, 0, q2, sm.fT, sm.bT, c, lane, w);
    __syncthreads();
    const int fin = (it == 5);
    bcjr_pass(sm.y1i, sm.A, sm.Lint, sm.perm, fin, q3, sm.fT, sm.bT, c, lane, w);
    __syncthreads();
  }

  // ---- Lint holds deinterleaved L2; coalesced store ----
  for (int i = tid; i < KLEN; i += TPR) outg[rb + i] = sm.Lint[i];
}

extern "C" void kernel_launch(void* const* d_in, const int* in_sizes, int n_in,
                              void* d_out, int out_size, void* d_ws, size_t ws_size,
                              hipStream_t stream) {
  (void)n_in; (void)d_ws; (void)ws_size; (void)out_size;
  const int* x    = (const int*)d_in[0];
  const float* n1 = (const float*)d_in[1];
  const float* n2 = (const float*)d_in[2];
  const float* n3 = (const float*)d_in[3];
  const int* perm = (const int*)d_in[4];
  float* out = (float*)d_out;
  const int K = in_sizes[4];       // 2048
  const int B = in_sizes[0] / K;   // 512 rows, one per block
  turbo_kernel<<<B, TPR, 0, stream>>>(x, n1, n2, n3, perm, out);
}

// Round 6
// 165.419 us; speedup vs baseline: 1.2213x; 1.2213x over previous
//
#include <hip/hip_runtime.h>

#define KLEN 2048
#define SCH 8           // trellis steps per thread
#define TPR 256         // threads per row (4 waves)
#define NEGV (-1e4f)

struct SM {
  float y1[KLEN];             // systematic, natural order
  float y1i[KLEN];            // systematic, interleaved
  float Lint[KLEN];           // La for decoder 1 (natural)
  float A[KLEN];              // La for decoder 2 (interleaved); bits staging
  unsigned short perm[KLEN];
  unsigned short invp[KLEN];
  float fT[4][16];            // per-wave totals (fwd total == bwd total)
  unsigned int eT[4][2];      // encoder wave totals
};

template <int CTRL>
__device__ __forceinline__ float dppf(float src) {
  return __int_as_float(__builtin_amdgcn_update_dpp(
      __float_as_int(src), __float_as_int(src), CTRL, 0xF, 0xF, false));
}

template <int CTRL>
__device__ __forceinline__ void shift16(const float (&X)[16], float (&T)[16]) {
#pragma unroll
  for (int e = 0; e < 16; ++e) T[e] = dppf<CTRL>(X[e]);
}

__device__ __forceinline__ void cp16(float (&D)[16], const float (&S)[16]) {
#pragma unroll
  for (int e = 0; e < 16; ++e) D[e] = S[e];
}

// Z = X (later) (x) Y (earlier), max-plus, row-major M[i*4+k]
__device__ __forceinline__ void comb(const float (&X)[16], const float (&Y)[16],
                                     float (&Z)[16]) {
#pragma unroll
  for (int i = 0; i < 4; ++i)
#pragma unroll
    for (int j = 0; j < 4; ++j)
      Z[i * 4 + j] = fmaxf(fmaxf(X[i * 4 + 0] + Y[0 * 4 + j], X[i * 4 + 1] + Y[1 * 4 + j]),
                           fmaxf(X[i * 4 + 2] + Y[2 * 4 + j], X[i * 4 + 3] + Y[3 * 4 + j]));
}

// f' = T (x) f  (column-vector pushed forward through later matrix T)
__device__ __forceinline__ void matcol(const float* T, float (&f)[4]) {
  float r0 = fmaxf(fmaxf(T[0]  + f[0], T[1]  + f[1]), fmaxf(T[2]  + f[2], T[3]  + f[3]));
  float r1 = fmaxf(fmaxf(T[4]  + f[0], T[5]  + f[1]), fmaxf(T[6]  + f[2], T[7]  + f[3]));
  float r2 = fmaxf(fmaxf(T[8]  + f[0], T[9]  + f[1]), fmaxf(T[10] + f[2], T[11] + f[3]));
  float r3 = fmaxf(fmaxf(T[12] + f[0], T[13] + f[1]), fmaxf(T[14] + f[2], T[15] + f[3]));
  f[0] = r0; f[1] = r1; f[2] = r2; f[3] = r3;
}

// u' = u (x) T  (row-vector pulled backward through earlier matrix T)
__device__ __forceinline__ void rowmat(float (&u)[4], const float* T) {
  float c0 = fmaxf(fmaxf(u[0] + T[0], u[1] + T[4]), fmaxf(u[2] + T[8],  u[3] + T[12]));
  float c1 = fmaxf(fmaxf(u[0] + T[1], u[1] + T[5]), fmaxf(u[2] + T[9],  u[3] + T[13]));
  float c2 = fmaxf(fmaxf(u[0] + T[2], u[1] + T[6]), fmaxf(u[2] + T[10], u[3] + T[14]));
  float c3 = fmaxf(fmaxf(u[0] + T[3], u[1] + T[7]), fmaxf(u[2] + T[11], u[3] + T[15]));
  u[0] = c0; u[1] = c1; u[2] = c2; u[3] = c3;
}

// chunk matrix over SCH steps: M[to][from], normalized to max 0
__device__ __forceinline__ void buildM(const float (&p)[SCH], const float (&q)[SCH],
                                       float (&M)[16]) {
  float ppq = p[0] + q[0], pmq = p[0] - q[0];
  M[0] = -ppq; M[1] =  ppq; M[2] = NEGV; M[3] = NEGV;
  M[4] = NEGV; M[5] = NEGV; M[6] =  pmq; M[7] = -pmq;
  M[8] =  ppq; M[9] = -ppq; M[10] = NEGV; M[11] = NEGV;
  M[12] = NEGV; M[13] = NEGV; M[14] = -pmq; M[15] =  pmq;
#pragma unroll
  for (int k = 1; k < SCH; ++k) {
    ppq = p[k] + q[k]; pmq = p[k] - q[k];
#pragma unroll
    for (int j = 0; j < 4; ++j) {
      float r0 = M[0 * 4 + j], r1 = M[1 * 4 + j], r2 = M[2 * 4 + j], r3 = M[3 * 4 + j];
      M[0 * 4 + j] = fmaxf(r0 - ppq, r1 + ppq);
      M[2 * 4 + j] = fmaxf(r0 + ppq, r1 - ppq);
      M[1 * 4 + j] = fmaxf(r2 + pmq, r3 - pmq);
      M[3 * 4 + j] = fmaxf(r2 - pmq, r3 + pmq);
    }
  }
  float mx = M[0];
#pragma unroll
  for (int e = 1; e < 16; ++e) mx = fmaxf(mx, M[e]);
#pragma unroll
  for (int e = 0; e < 16; ++e) M[e] -= mx;
}

// one BCJR pass: 4 waves x 64 lanes x SCH steps; matrix scan + vector tails
__device__ __forceinline__ void bcjr_pass(
    const float* ys, const float* La, float* dst, const unsigned short* widx,
    int finalLLR, const float (&q)[SCH], float (&fT)[4][16],
    int c, int lane, int w) {
  const int base = c * SCH;
  float p[SCH];
  {
    const float4* y4 = (const float4*)(ys + base);
    const float4* l4 = (const float4*)(La + base);
#pragma unroll
    for (int k = 0; k < SCH / 4; ++k) {
      float4 yv = y4[k], lv = l4[k];
      p[4 * k + 0] = yv.x + 0.5f * lv.x;
      p[4 * k + 1] = yv.y + 0.5f * lv.y;
      p[4 * k + 2] = yv.z + 0.5f * lv.z;
      p[4 * k + 3] = yv.w + 0.5f * lv.w;
    }
  }

  float P[16];
  buildM(p, q, P);
  float Q[16];
  cp16(Q, P);

  const int rl = lane & 15;
  const int row = lane >> 4;

  // ---- fwd inclusive prefix scan, full 64 lanes (6 DPP levels) ----
  {
    float T[16], N[16];
    shift16<0x111>(P, T); if (rl >= 1) { comb(P, T, N); cp16(P, N); }
    shift16<0x112>(P, T); if (rl >= 2) { comb(P, T, N); cp16(P, N); }
    shift16<0x114>(P, T); if (rl >= 4) { comb(P, T, N); cp16(P, N); }
    shift16<0x118>(P, T); if (rl >= 8) { comb(P, T, N); cp16(P, N); }
    shift16<0x142>(P, T); if (row & 1)  { comb(P, T, N); cp16(P, N); }  // bcast15
    shift16<0x143>(P, T); if (row >= 2) { comb(P, T, N); cp16(P, N); }  // bcast31
  }
  // ---- bwd inclusive suffix scan, IN-ROW ONLY (4 DPP levels) ----
  {
    float T[16], N[16];
    shift16<0x101>(Q, T); if (rl <= 14) { comb(T, Q, N); cp16(Q, N); }
    shift16<0x102>(Q, T); if (rl <= 13) { comb(T, Q, N); cp16(Q, N); }
    shift16<0x104>(Q, T); if (rl <= 11) { comb(T, Q, N); cp16(Q, N); }
    shift16<0x108>(Q, T); if (rl <= 7)  { comb(T, Q, N); cp16(Q, N); }
  }

  // ---- wave total (fwd total == bwd total) -> LDS ----
  if (lane == 63) cp16(fT[w], P);
  __syncthreads();

  // ---- forward vector chain: f = col0 of product of earlier waves' totals ----
  float f[4];
  if (w == 0) { f[0] = 0.f; f[1] = NEGV; f[2] = NEGV; f[3] = NEGV; }
  else {
    f[0] = fT[0][0]; f[1] = fT[0][4]; f[2] = fT[0][8]; f[3] = fT[0][12];
    if (w >= 2) matcol(fT[1], f);
    if (w >= 3) matcol(fT[2], f);
  }
  // ---- backward vector chain: u = colmax over later waves' totals ----
  float u[4];
  if (w == 3) { u[0] = u[1] = u[2] = u[3] = 0.f; }
  else {
    const float* T3 = fT[3];
#pragma unroll
    for (int j = 0; j < 4; ++j)
      u[j] = fmaxf(fmaxf(T3[j], T3[4 + j]), fmaxf(T3[8 + j], T3[12 + j]));
    if (w <= 1) rowmat(u, fT[2]);
    if (w == 0) rowmat(u, fT[1]);
  }
  // ---- extend u through later rows' totals within this wave ----
#pragma unroll
  for (int jj = 3; jj >= 1; --jj) {
    float T[16];
#pragma unroll
    for (int e = 0; e < 16; ++e) T[e] = __shfl(Q[e], jj << 4);  // lane jj*16 holds row jj total
    if (row < jj) rowmat(u, T);
  }

  // ---- alpha at chunk start: v = P (x) f (inclusive), then shift by one lane ----
  float a[4];
  {
    float v0 = fmaxf(fmaxf(P[0]  + f[0], P[1]  + f[1]), fmaxf(P[2]  + f[2], P[3]  + f[3]));
    float v1 = fmaxf(fmaxf(P[4]  + f[0], P[5]  + f[1]), fmaxf(P[6]  + f[2], P[7]  + f[3]));
    float v2 = fmaxf(fmaxf(P[8]  + f[0], P[9]  + f[1]), fmaxf(P[10] + f[2], P[11] + f[3]));
    float v3 = fmaxf(fmaxf(P[12] + f[0], P[13] + f[1]), fmaxf(P[14] + f[2], P[15] + f[3]));
    float a0 = __shfl(v0, lane - 1), a1 = __shfl(v1, lane - 1);
    float a2 = __shfl(v2, lane - 1), a3 = __shfl(v3, lane - 1);
    if (lane == 0) { a0 = f[0]; a1 = f[1]; a2 = f[2]; a3 = f[3]; }
    a[0] = 0.f; a[1] = a1 - a0; a[2] = a2 - a0; a[3] = a3 - a0;
  }

  // ---- beta at chunk end: z = u (x) Q (inclusive suffix colmax), shift by one ----
  float b[4];
  {
    float z0 = fmaxf(fmaxf(u[0] + Q[0], u[1] + Q[4]), fmaxf(u[2] + Q[8],  u[3] + Q[12]));
    float z1 = fmaxf(fmaxf(u[0] + Q[1], u[1] + Q[5]), fmaxf(u[2] + Q[9],  u[3] + Q[13]));
    float z2 = fmaxf(fmaxf(u[0] + Q[2], u[1] + Q[6]), fmaxf(u[2] + Q[10], u[3] + Q[14]));
    float z3 = fmaxf(fmaxf(u[0] + Q[3], u[1] + Q[7]), fmaxf(u[2] + Q[11], u[3] + Q[15]));
    float b0 = __shfl(z0, lane + 1), b1 = __shfl(z1, lane + 1);
    float b2 = __shfl(z2, lane + 1), b3 = __shfl(z3, lane + 1);
    if (lane == 63) { b0 = u[0]; b1 = u[1]; b2 = u[2]; b3 = u[3]; }
    b[0] = 0.f; b[1] = b1 - b0; b[2] = b2 - b0; b[3] = b3 - b0;
  }

  // ---- local beta walk ----
  float bet[SCH][4];
  bet[SCH - 1][0] = b[0]; bet[SCH - 1][1] = b[1];
  bet[SCH - 1][2] = b[2]; bet[SCH - 1][3] = b[3];
#pragma unroll
  for (int k = SCH - 1; k >= 1; --k) {
    float ppq = p[k] + q[k], pmq = p[k] - q[k];
    float B0 = bet[k][0], B1 = bet[k][1], B2 = bet[k][2], B3 = bet[k][3];
    bet[k - 1][0] = fmaxf(B0 - ppq, B2 + ppq);
    bet[k - 1][1] = fmaxf(B2 - ppq, B0 + ppq);
    bet[k - 1][2] = fmaxf(B3 - pmq, B1 + pmq);
    bet[k - 1][3] = fmaxf(B1 - pmq, B3 + pmq);
  }

  // ---- alpha walk + LLR + scattered write ----
#pragma unroll
  for (int k = 0; k < SCH; ++k) {
    float ppq = p[k] + q[k], pmq = p[k] - q[k];
    float B0 = bet[k][0], B1 = bet[k][1], B2 = bet[k][2], B3 = bet[k][3];
    float m1 = fmaxf(fmaxf(a[0] + ppq + B2, a[1] + ppq + B0),
                     fmaxf(a[2] + pmq + B1, a[3] + pmq + B3));
    float m0 = fmaxf(fmaxf(a[0] - ppq + B0, a[1] - ppq + B2),
                     fmaxf(a[2] - pmq + B3, a[3] - pmq + B1));
    float llr = m1 - m0;
    float val = finalLLR ? llr : (llr - 2.f * p[k]);
    dst[widx[base + k]] = val;
    float a0 = a[0], a1 = a[1], a2 = a[2], a3 = a[3];
    a[0] = fmaxf(a0 - ppq, a1 + ppq);
    a[2] = fmaxf(a0 + ppq, a1 - ppq);
    a[1] = fmaxf(a2 + pmq, a3 - pmq);
    a[3] = fmaxf(a2 - pmq, a3 + pmq);
  }
}

__device__ __forceinline__ unsigned fsm_compose(unsigned f, unsigned g) {
  unsigned nm = 0;
#pragma unroll
  for (int s = 0; s < 4; ++s) {
    unsigned gs = (g >> (8 * s)) & 3u;
    nm |= ((f >> (8 * gs)) & 0xFFu) << (8 * s);
  }
  return nm;
}

__global__ __launch_bounds__(TPR, 2) void turbo_kernel(
    const int* __restrict__ xg, const float* __restrict__ n1g,
    const float* __restrict__ n2g, const float* __restrict__ n3g,
    const int* __restrict__ pg, float* __restrict__ outg) {
  __shared__ SM sm;
  const int tid = threadIdx.x;
  const int c = tid, lane = tid & 63, w = tid >> 6;
  const size_t rb = (size_t)blockIdx.x * KLEN;

  // ---- load inputs ----
  int* Ai = (int*)sm.A;
  for (int i = tid; i < KLEN; i += TPR) {
    sm.perm[i] = (unsigned short)pg[i];
    int xv = xg[rb + i];
    Ai[i] = xv;
    sm.y1[i] = (2.f * xv - 1.f) + n1g[rb + i];
    sm.Lint[i] = 0.f;
  }
  float q2[SCH], q3[SCH];
  {
    size_t g0 = rb + (size_t)c * SCH;
#pragma unroll
    for (int k = 0; k < SCH; ++k) { q2[k] = n2g[g0 + k]; q3[k] = n3g[g0 + k]; }
  }
  __syncthreads();

  // ---- one-time: invp, interleaved systematic ----
  for (int i = tid; i < KLEN; i += TPR) {
    sm.invp[sm.perm[i]] = (unsigned short)i;
    sm.y1i[i] = sm.y1[sm.perm[i]];
  }

  // ---- RSC encode via FSM hierarchical scan ----
  unsigned ub1 = 0, ub2 = 0;
#pragma unroll
  for (int k = 0; k < SCH; ++k) {
    int t = c * SCH + k;
    ub1 |= (unsigned)(Ai[t] & 1) << k;
    ub2 |= (unsigned)(Ai[sm.perm[t]] & 1) << k;
  }
  unsigned m1 = 0x03020100u, m2 = 0x03020100u;
#pragma unroll
  for (int k = 0; k < SCH; ++k) {
    unsigned st1 = ((ub1 >> k) & 1) ? 0x03010002u : 0x01030200u;
    unsigned st2 = ((ub2 >> k) & 1) ? 0x03010002u : 0x01030200u;
    m1 = fsm_compose(st1, m1);
    m2 = fsm_compose(st2, m2);
  }
#pragma unroll
  for (int i = 0; i < 6; ++i) {
    const int d = 1 << i;
    unsigned t1 = __shfl_up(m1, d), t2 = __shfl_up(m2, d);
    if (lane >= d) { m1 = fsm_compose(m1, t1); m2 = fsm_compose(m2, t2); }
  }
  if (lane == 63) { sm.eT[w][0] = m1; sm.eT[w][1] = m2; }
  __syncthreads();
  {
    unsigned W1 = 0x03020100u, W2 = 0x03020100u;
    if (w >= 1) { W1 = sm.eT[0][0]; W2 = sm.eT[0][1]; }
    if (w >= 2) { W1 = fsm_compose(sm.eT[1][0], W1); W2 = fsm_compose(sm.eT[1][1], W2); }
    if (w >= 3) { W1 = fsm_compose(sm.eT[2][0], W1); W2 = fsm_compose(sm.eT[2][1], W2); }
    unsigned f1 = fsm_compose(m1, W1), f2 = fsm_compose(m2, W2);
    unsigned pf1 = __shfl_up(f1, 1), pf2 = __shfl_up(f2, 1);
    int s1 = (c == 0) ? 0 : (lane == 0 ? (int)(W1 & 3u) : (int)(pf1 & 3u));
    int s2 = (c == 0) ? 0 : (lane == 0 ? (int)(W2 & 3u) : (int)(pf2 & 3u));
#pragma unroll
    for (int k = 0; k < SCH; ++k) {
      { int u = (ub1 >> k) & 1, a = u ^ (s1 >> 1) ^ (s1 & 1), par = a ^ (s1 & 1);
        q2[k] += 2.f * par - 1.f; s1 = (a << 1) | (s1 >> 1); }
      { int u = (ub2 >> k) & 1, a = u ^ (s2 >> 1) ^ (s2 & 1), par = a ^ (s2 & 1);
        q3[k] += 2.f * par - 1.f; s2 = (a << 1) | (s2 >> 1); }
    }
  }
  __syncthreads();  // bits consumed; A becomes interleaved-La buffer

  // ---- 6 turbo iterations ----
#pragma unroll 1
  for (int it = 0; it < 6; ++it) {
    bcjr_pass(sm.y1, sm.Lint, sm.A, sm.invp, 0, q2, sm.fT, c, lane, w);
    __syncthreads();
    const int fin = (it == 5);
    bcjr_pass(sm.y1i, sm.A, sm.Lint, sm.perm, fin, q3, sm.fT, c, lane, w);
    __syncthreads();
  }

  // ---- Lint holds deinterleaved L2; coalesced store ----
  for (int i = tid; i < KLEN; i += TPR) outg[rb + i] = sm.Lint[i];
}

extern "C" void kernel_launch(void* const* d_in, const int* in_sizes, int n_in,
                              void* d_out, int out_size, void* d_ws, size_t ws_size,
                              hipStream_t stream) {
  (void)n_in; (void)d_ws; (void)ws_size; (void)out_size;
  const int* x    = (const int*)d_in[0];
  const float* n1 = (const float*)d_in[1];
  const float* n2 = (const float*)d_in[2];
  const float* n3 = (const float*)d_in[3];
  const int* perm = (const int*)d_in[4];
  float* out = (float*)d_out;
  const int K = in_sizes[4];       // 2048
  const int B = in_sizes[0] / K;   // 512 rows, one per block
  turbo_kernel<<<B, TPR, 0, stream>>>(x, n1, n2, n3, perm, out);
}

// Round 7
// 163.513 us; speedup vs baseline: 1.2356x; 1.0117x over previous
//
#include <hip/hip_runtime.h>

#define KLEN 2048
#define SCH 8           // trellis steps per thread
#define TPR 256         // threads per row (4 waves)
#define NEGV (-1e4f)

struct SM {
  float y1[KLEN];             // systematic, natural order
  float y1i[KLEN];            // systematic, interleaved
  float Lint[KLEN];           // La for decoder 1 (natural)
  float A[KLEN];              // La for decoder 2 (interleaved); bits staging
  unsigned short perm[KLEN];
  unsigned short invp[KLEN];
  float fT[4][16];            // per-wave totals (fwd total == bwd total)
  unsigned int eT[4][2];      // encoder wave totals
};

__device__ __forceinline__ float max4(float a, float b, float c, float d) {
  return fmaxf(fmaxf(fmaxf(a, b), c), d);   // v_max3 + v_max
}

template <int CTRL>
__device__ __forceinline__ float dppf(float src) {
  return __int_as_float(__builtin_amdgcn_update_dpp(
      __float_as_int(src), __float_as_int(src), CTRL, 0xF, 0xF, false));
}

template <int CTRL>
__device__ __forceinline__ void shift16(const float (&X)[16], float (&T)[16]) {
#pragma unroll
  for (int e = 0; e < 16; ++e) T[e] = dppf<CTRL>(X[e]);
}

__device__ __forceinline__ void cp16(float (&D)[16], const float (&S)[16]) {
#pragma unroll
  for (int e = 0; e < 16; ++e) D[e] = S[e];
}

// Z = X (later) (x) Y (earlier), max-plus, row-major M[i*4+k]
__device__ __forceinline__ void comb(const float (&X)[16], const float (&Y)[16],
                                     float (&Z)[16]) {
#pragma unroll
  for (int i = 0; i < 4; ++i)
#pragma unroll
    for (int j = 0; j < 4; ++j)
      Z[i * 4 + j] = max4(X[i * 4 + 0] + Y[0 * 4 + j], X[i * 4 + 1] + Y[1 * 4 + j],
                          X[i * 4 + 2] + Y[2 * 4 + j], X[i * 4 + 3] + Y[3 * 4 + j]);
}

// f' = T (x) f  (column-vector pushed forward through later matrix T)
__device__ __forceinline__ void matcol(const float* T, float (&f)[4]) {
  float r0 = max4(T[0]  + f[0], T[1]  + f[1], T[2]  + f[2], T[3]  + f[3]);
  float r1 = max4(T[4]  + f[0], T[5]  + f[1], T[6]  + f[2], T[7]  + f[3]);
  float r2 = max4(T[8]  + f[0], T[9]  + f[1], T[10] + f[2], T[11] + f[3]);
  float r3 = max4(T[12] + f[0], T[13] + f[1], T[14] + f[2], T[15] + f[3]);
  f[0] = r0; f[1] = r1; f[2] = r2; f[3] = r3;
}

// u' = u (x) T  (row-vector pulled backward through earlier matrix T)
__device__ __forceinline__ void rowmat(float (&u)[4], const float* T) {
  float c0 = max4(u[0] + T[0], u[1] + T[4], u[2] + T[8],  u[3] + T[12]);
  float c1 = max4(u[0] + T[1], u[1] + T[5], u[2] + T[9],  u[3] + T[13]);
  float c2 = max4(u[0] + T[2], u[1] + T[6], u[2] + T[10], u[3] + T[14]);
  float c3 = max4(u[0] + T[3], u[1] + T[7], u[2] + T[11], u[3] + T[15]);
  u[0] = c0; u[1] = c1; u[2] = c2; u[3] = c3;
}

// chunk matrix over SCH steps: M[to][from]. Steps 0+1 fused (step-1 has no max:
// each column has exactly 2 real sources after step 0). NO normalization.
__device__ __forceinline__ void buildM(const float (&p)[SCH], const float (&q)[SCH],
                                       float (&M)[16]) {
  const float x0 = p[0] + q[0], y0 = p[0] - q[0];
  const float x1 = p[1] + q[1], y1 = p[1] - q[1];
  M[0]  = -x0 - x1;  M[4]  =  x0 + y1;  M[8]  = -x0 + x1;  M[12] =  x0 - y1;  // col0
  M[1]  =  x0 - x1;  M[5]  = -x0 + y1;  M[9]  =  x0 + x1;  M[13] = -x0 - y1;  // col1
  M[2]  =  y0 + x1;  M[6]  = -y0 - y1;  M[10] =  y0 - x1;  M[14] = -y0 + y1;  // col2
  M[3]  = -y0 + x1;  M[7]  =  y0 - y1;  M[11] = -y0 - x1;  M[15] =  y0 + y1;  // col3
#pragma unroll
  for (int k = 2; k < SCH; ++k) {
    float ppq = p[k] + q[k], pmq = p[k] - q[k];
#pragma unroll
    for (int j = 0; j < 4; ++j) {
      float r0 = M[0 * 4 + j], r1 = M[1 * 4 + j], r2 = M[2 * 4 + j], r3 = M[3 * 4 + j];
      M[0 * 4 + j] = fmaxf(r0 - ppq, r1 + ppq);
      M[2 * 4 + j] = fmaxf(r0 + ppq, r1 - ppq);
      M[1 * 4 + j] = fmaxf(r2 + pmq, r3 - pmq);
      M[3 * 4 + j] = fmaxf(r2 - pmq, r3 + pmq);
    }
  }
}

// one BCJR pass: 4 waves x 64 lanes x SCH steps; matrix scan + vector tails
__device__ __forceinline__ void bcjr_pass(
    const float* ys, const float* La, float* dst, const unsigned short* widx,
    int finalLLR, const float (&q)[SCH], float (&fT)[4][16],
    int c, int lane, int w) {
  const int base = c * SCH;
  float p[SCH];
  {
    const float4* y4 = (const float4*)(ys + base);
    const float4* l4 = (const float4*)(La + base);
#pragma unroll
    for (int k = 0; k < SCH / 4; ++k) {
      float4 yv = y4[k], lv = l4[k];
      p[4 * k + 0] = yv.x + 0.5f * lv.x;
      p[4 * k + 1] = yv.y + 0.5f * lv.y;
      p[4 * k + 2] = yv.z + 0.5f * lv.z;
      p[4 * k + 3] = yv.w + 0.5f * lv.w;
    }
  }

  float P[16];
  buildM(p, q, P);
  float Q[16];
  cp16(Q, P);

  const int rl = lane & 15;
  const int row = lane >> 4;

  // ---- fwd inclusive prefix scan, full 64 lanes (6 DPP levels) ----
  {
    float T[16], N[16];
    shift16<0x111>(P, T); if (rl >= 1) { comb(P, T, N); cp16(P, N); }
    shift16<0x112>(P, T); if (rl >= 2) { comb(P, T, N); cp16(P, N); }
    shift16<0x114>(P, T); if (rl >= 4) { comb(P, T, N); cp16(P, N); }
    shift16<0x118>(P, T); if (rl >= 8) { comb(P, T, N); cp16(P, N); }
    shift16<0x142>(P, T); if (row & 1)  { comb(P, T, N); cp16(P, N); }  // bcast15
    shift16<0x143>(P, T); if (row >= 2) { comb(P, T, N); cp16(P, N); }  // bcast31
  }
  // ---- bwd inclusive suffix scan, IN-ROW ONLY (4 DPP levels) ----
  {
    float T[16], N[16];
    shift16<0x101>(Q, T); if (rl <= 14) { comb(T, Q, N); cp16(Q, N); }
    shift16<0x102>(Q, T); if (rl <= 13) { comb(T, Q, N); cp16(Q, N); }
    shift16<0x104>(Q, T); if (rl <= 11) { comb(T, Q, N); cp16(Q, N); }
    shift16<0x108>(Q, T); if (rl <= 7)  { comb(T, Q, N); cp16(Q, N); }
  }

  // ---- wave total (fwd total == bwd total) -> LDS ----
  if (lane == 63) cp16(fT[w], P);
  __syncthreads();

  // ---- forward vector chain: f = col0 of product of earlier waves' totals ----
  float f[4];
  if (w == 0) { f[0] = 0.f; f[1] = NEGV; f[2] = NEGV; f[3] = NEGV; }
  else {
    f[0] = fT[0][0]; f[1] = fT[0][4]; f[2] = fT[0][8]; f[3] = fT[0][12];
    if (w >= 2) matcol(fT[1], f);
    if (w >= 3) matcol(fT[2], f);
  }
  // ---- backward vector chain: u = colmax over later waves' totals ----
  float u[4];
  if (w == 3) { u[0] = u[1] = u[2] = u[3] = 0.f; }
  else {
    const float* T3 = fT[3];
#pragma unroll
    for (int j = 0; j < 4; ++j)
      u[j] = max4(T3[j], T3[4 + j], T3[8 + j], T3[12 + j]);
    if (w <= 1) rowmat(u, fT[2]);
    if (w == 0) rowmat(u, fT[1]);
  }
  // ---- extend u through later rows' totals within this wave ----
#pragma unroll
  for (int jj = 3; jj >= 1; --jj) {
    float T[16];
#pragma unroll
    for (int e = 0; e < 16; ++e) T[e] = __shfl(Q[e], jj << 4);  // lane jj*16 = row jj total
    if (row < jj) rowmat(u, T);
  }

  // ---- alpha at chunk start: v = P (x) f (inclusive), then shift by one lane ----
  float a[4];
  {
    float v0 = max4(P[0]  + f[0], P[1]  + f[1], P[2]  + f[2], P[3]  + f[3]);
    float v1 = max4(P[4]  + f[0], P[5]  + f[1], P[6]  + f[2], P[7]  + f[3]);
    float v2 = max4(P[8]  + f[0], P[9]  + f[1], P[10] + f[2], P[11] + f[3]);
    float v3 = max4(P[12] + f[0], P[13] + f[1], P[14] + f[2], P[15] + f[3]);
    float a0 = __shfl(v0, lane - 1), a1 = __shfl(v1, lane - 1);
    float a2 = __shfl(v2, lane - 1), a3 = __shfl(v3, lane - 1);
    if (lane == 0) { a0 = f[0]; a1 = f[1]; a2 = f[2]; a3 = f[3]; }
    a[0] = 0.f; a[1] = a1 - a0; a[2] = a2 - a0; a[3] = a3 - a0;
  }

  // ---- beta at chunk end: z = u (x) Q (inclusive suffix colmax), shift by one ----
  float b[4];
  {
    float z0 = max4(u[0] + Q[0], u[1] + Q[4], u[2] + Q[8],  u[3] + Q[12]);
    float z1 = max4(u[0] + Q[1], u[1] + Q[5], u[2] + Q[9],  u[3] + Q[13]);
    float z2 = max4(u[0] + Q[2], u[1] + Q[6], u[2] + Q[10], u[3] + Q[14]);
    float z3 = max4(u[0] + Q[3], u[1] + Q[7], u[2] + Q[11], u[3] + Q[15]);
    float b0 = __shfl(z0, lane + 1), b1 = __shfl(z1, lane + 1);
    float b2 = __shfl(z2, lane + 1), b3 = __shfl(z3, lane + 1);
    if (lane == 63) { b0 = u[0]; b1 = u[1]; b2 = u[2]; b3 = u[3]; }
    b[0] = 0.f; b[1] = b1 - b0; b[2] = b2 - b0; b[3] = b3 - b0;
  }

  // ---- local beta walk ----
  float bet[SCH][4];
  bet[SCH - 1][0] = b[0]; bet[SCH - 1][1] = b[1];
  bet[SCH - 1][2] = b[2]; bet[SCH - 1][3] = b[3];
#pragma unroll
  for (int k = SCH - 1; k >= 1; --k) {
    float ppq = p[k] + q[k], pmq = p[k] - q[k];
    float B0 = bet[k][0], B1 = bet[k][1], B2 = bet[k][2], B3 = bet[k][3];
    bet[k - 1][0] = fmaxf(B0 - ppq, B2 + ppq);
    bet[k - 1][1] = fmaxf(B2 - ppq, B0 + ppq);
    bet[k - 1][2] = fmaxf(B3 - pmq, B1 + pmq);
    bet[k - 1][3] = fmaxf(B1 - pmq, B3 + pmq);
  }

  // ---- alpha walk + LLR + scattered write (shared butterfly sums) ----
#pragma unroll
  for (int k = 0; k < SCH; ++k) {
    float ppq = p[k] + q[k], pmq = p[k] - q[k];
    float s0m = a[0] - ppq, s1p = a[1] + ppq, s0p = a[0] + ppq, s1m = a[1] - ppq;
    float s2p = a[2] + pmq, s3m = a[3] - pmq, s2m = a[2] - pmq, s3p = a[3] + pmq;
    float B0 = bet[k][0], B1 = bet[k][1], B2 = bet[k][2], B3 = bet[k][3];
    float m1 = max4(s0p + B2, s1p + B0, s2p + B1, s3p + B3);
    float m0 = max4(s0m + B0, s1m + B2, s2m + B3, s3m + B1);
    float llr = m1 - m0;
    float val = finalLLR ? llr : (llr - 2.f * p[k]);
    dst[widx[base + k]] = val;
    a[0] = fmaxf(s0m, s1p);
    a[2] = fmaxf(s0p, s1m);
    a[1] = fmaxf(s2p, s3m);
    a[3] = fmaxf(s2m, s3p);
  }
}

__device__ __forceinline__ unsigned fsm_compose(unsigned f, unsigned g) {
  unsigned nm = 0;
#pragma unroll
  for (int s = 0; s < 4; ++s) {
    unsigned gs = (g >> (8 * s)) & 3u;
    nm |= ((f >> (8 * gs)) & 0xFFu) << (8 * s);
  }
  return nm;
}

__global__ __launch_bounds__(TPR, 2) void turbo_kernel(
    const int* __restrict__ xg, const float* __restrict__ n1g,
    const float* __restrict__ n2g, const float* __restrict__ n3g,
    const int* __restrict__ pg, float* __restrict__ outg) {
  __shared__ SM sm;
  const int tid = threadIdx.x;
  const int c = tid, lane = tid & 63, w = tid >> 6;
  const size_t rb = (size_t)blockIdx.x * KLEN;

  // ---- load inputs ----
  int* Ai = (int*)sm.A;
  for (int i = tid; i < KLEN; i += TPR) {
    sm.perm[i] = (unsigned short)pg[i];
    int xv = xg[rb + i];
    Ai[i] = xv;
    sm.y1[i] = (2.f * xv - 1.f) + n1g[rb + i];
    sm.Lint[i] = 0.f;
  }
  float q2[SCH], q3[SCH];
  {
    size_t g0 = rb + (size_t)c * SCH;
#pragma unroll
    for (int k = 0; k < SCH; ++k) { q2[k] = n2g[g0 + k]; q3[k] = n3g[g0 + k]; }
  }
  __syncthreads();

  // ---- one-time: invp, interleaved systematic ----
  for (int i = tid; i < KLEN; i += TPR) {
    sm.invp[sm.perm[i]] = (unsigned short)i;
    sm.y1i[i] = sm.y1[sm.perm[i]];
  }

  // ---- RSC encode via FSM hierarchical scan ----
  unsigned ub1 = 0, ub2 = 0;
#pragma unroll
  for (int k = 0; k < SCH; ++k) {
    int t = c * SCH + k;
    ub1 |= (unsigned)(Ai[t] & 1) << k;
    ub2 |= (unsigned)(Ai[sm.perm[t]] & 1) << k;
  }
  unsigned m1 = 0x03020100u, m2 = 0x03020100u;
#pragma unroll
  for (int k = 0; k < SCH; ++k) {
    unsigned st1 = ((ub1 >> k) & 1) ? 0x03010002u : 0x01030200u;
    unsigned st2 = ((ub2 >> k) & 1) ? 0x03010002u : 0x01030200u;
    m1 = fsm_compose(st1, m1);
    m2 = fsm_compose(st2, m2);
  }
#pragma unroll
  for (int i = 0; i < 6; ++i) {
    const int d = 1 << i;
    unsigned t1 = __shfl_up(m1, d), t2 = __shfl_up(m2, d);
    if (lane >= d) { m1 = fsm_compose(m1, t1); m2 = fsm_compose(m2, t2); }
  }
  if (lane == 63) { sm.eT[w][0] = m1; sm.eT[w][1] = m2; }
  __syncthreads();
  {
    unsigned W1 = 0x03020100u, W2 = 0x03020100u;
    if (w >= 1) { W1 = sm.eT[0][0]; W2 = sm.eT[0][1]; }
    if (w >= 2) { W1 = fsm_compose(sm.eT[1][0], W1); W2 = fsm_compose(sm.eT[1][1], W2); }
    if (w >= 3) { W1 = fsm_compose(sm.eT[2][0], W1); W2 = fsm_compose(sm.eT[2][1], W2); }
    unsigned f1 = fsm_compose(m1, W1), f2 = fsm_compose(m2, W2);
    unsigned pf1 = __shfl_up(f1, 1), pf2 = __shfl_up(f2, 1);
    int s1 = (c == 0) ? 0 : (lane == 0 ? (int)(W1 & 3u) : (int)(pf1 & 3u));
    int s2 = (c == 0) ? 0 : (lane == 0 ? (int)(W2 & 3u) : (int)(pf2 & 3u));
#pragma unroll
    for (int k = 0; k < SCH; ++k) {
      { int u = (ub1 >> k) & 1, a = u ^ (s1 >> 1) ^ (s1 & 1), par = a ^ (s1 & 1);
        q2[k] += 2.f * par - 1.f; s1 = (a << 1) | (s1 >> 1); }
      { int u = (ub2 >> k) & 1, a = u ^ (s2 >> 1) ^ (s2 & 1), par = a ^ (s2 & 1);
        q3[k] += 2.f * par - 1.f; s2 = (a << 1) | (s2 >> 1); }
    }
  }
  __syncthreads();  // bits consumed; A becomes interleaved-La buffer

  // ---- 6 turbo iterations ----
#pragma unroll 1
  for (int it = 0; it < 6; ++it) {
    bcjr_pass(sm.y1, sm.Lint, sm.A, sm.invp, 0, q2, sm.fT, c, lane, w);
    __syncthreads();
    const int fin = (it == 5);
    bcjr_pass(sm.y1i, sm.A, sm.Lint, sm.perm, fin, q3, sm.fT, c, lane, w);
    __syncthreads();
  }

  // ---- Lint holds deinterleaved L2; coalesced store ----
  for (int i = tid; i < KLEN; i += TPR) outg[rb + i] = sm.Lint[i];
}

extern "C" void kernel_launch(void* const* d_in, const int* in_sizes, int n_in,
                              void* d_out, int out_size, void* d_ws, size_t ws_size,
                              hipStream_t stream) {
  (void)n_in; (void)d_ws; (void)ws_size; (void)out_size;
  const int* x    = (const int*)d_in[0];
  const float* n1 = (const float*)d_in[1];
  const float* n2 = (const float*)d_in[2];
  const float* n3 = (const float*)d_in[3];
  const int* perm = (const int*)d_in[4];
  float* out = (float*)d_out;
  const int K = in_sizes[4];       // 2048
  const int B = in_sizes[0] / K;   // 512 rows, one per block
  turbo_kernel<<<B, TPR, 0, stream>>>(x, n1, n2, n3, perm, out);
}

// Round 8
// 155.264 us; speedup vs baseline: 1.3012x; 1.0531x over previous
//
#include <hip/hip_runtime.h>

#define KLEN 2048
#define SCH 8           // trellis steps per thread
#define TPR 256         // threads per row (4 waves)
#define NEGV (-1e4f)

struct SM {
  float y1[KLEN];             // systematic, natural order
  float y1i[KLEN];            // systematic, interleaved
  float Lint[KLEN];           // La for decoder 1 (natural)
  float A[KLEN];              // La for decoder 2 (interleaved); bits staging
  unsigned short perm[KLEN];
  unsigned short invp[KLEN];
  float fT[4][16];            // per-wave totals (fwd total == bwd total)
  unsigned int eT[4][2];      // encoder wave totals
};

__device__ __forceinline__ float max4(float a, float b, float c, float d) {
  return fmaxf(fmaxf(fmaxf(a, b), c), d);   // v_max3 + v_max
}

// DPP shift with old = inline 0, bound_ctrl=1: no register tie, invalid lanes -> 0
// (those lanes are exec-predicated off in every consumer).
template <int CTRL>
__device__ __forceinline__ float dppf(float src) {
  return __int_as_float(__builtin_amdgcn_update_dpp(
      0, __float_as_int(src), CTRL, 0xF, 0xF, true));
}

template <int CTRL>
__device__ __forceinline__ void shift16(const float (&X)[16], float (&T)[16]) {
#pragma unroll
  for (int e = 0; e < 16; ++e) T[e] = dppf<CTRL>(X[e]);
}

__device__ __forceinline__ void cp16(float (&D)[16], const float (&S)[16]) {
#pragma unroll
  for (int e = 0; e < 16; ++e) D[e] = S[e];
}

// Z = X (later) (x) Y (earlier), max-plus, row-major M[i*4+k]
__device__ __forceinline__ void comb(const float (&X)[16], const float (&Y)[16],
                                     float (&Z)[16]) {
#pragma unroll
  for (int i = 0; i < 4; ++i)
#pragma unroll
    for (int j = 0; j < 4; ++j)
      Z[i * 4 + j] = max4(X[i * 4 + 0] + Y[0 * 4 + j], X[i * 4 + 1] + Y[1 * 4 + j],
                          X[i * 4 + 2] + Y[2 * 4 + j], X[i * 4 + 3] + Y[3 * 4 + j]);
}

// f' = T (x) f  (column-vector pushed forward through later matrix T)
__device__ __forceinline__ void matcol(const float* T, float (&f)[4]) {
  float r0 = max4(T[0]  + f[0], T[1]  + f[1], T[2]  + f[2], T[3]  + f[3]);
  float r1 = max4(T[4]  + f[0], T[5]  + f[1], T[6]  + f[2], T[7]  + f[3]);
  float r2 = max4(T[8]  + f[0], T[9]  + f[1], T[10] + f[2], T[11] + f[3]);
  float r3 = max4(T[12] + f[0], T[13] + f[1], T[14] + f[2], T[15] + f[3]);
  f[0] = r0; f[1] = r1; f[2] = r2; f[3] = r3;
}

// u' = u (x) T  (row-vector pulled backward through earlier matrix T)
__device__ __forceinline__ void rowmat(float (&u)[4], const float* T) {
  float c0 = max4(u[0] + T[0], u[1] + T[4], u[2] + T[8],  u[3] + T[12]);
  float c1 = max4(u[0] + T[1], u[1] + T[5], u[2] + T[9],  u[3] + T[13]);
  float c2 = max4(u[0] + T[2], u[1] + T[6], u[2] + T[10], u[3] + T[14]);
  float c3 = max4(u[0] + T[3], u[1] + T[7], u[2] + T[11], u[3] + T[15]);
  u[0] = c0; u[1] = c1; u[2] = c2; u[3] = c3;
}

// chunk matrix over SCH steps from butterfly terms x=p+q, y=p-q.
// Steps 0+1 fused (pure adds). NO normalization.
__device__ __forceinline__ void buildM(const float (&x)[SCH], const float (&y)[SCH],
                                       float (&M)[16]) {
  const float x0 = x[0], y0 = y[0], x1 = x[1], y1 = y[1];
  M[0]  = -x0 - x1;  M[4]  =  x0 + y1;  M[8]  = -x0 + x1;  M[12] =  x0 - y1;  // col0
  M[1]  =  x0 - x1;  M[5]  = -x0 + y1;  M[9]  =  x0 + x1;  M[13] = -x0 - y1;  // col1
  M[2]  =  y0 + x1;  M[6]  = -y0 - y1;  M[10] =  y0 - x1;  M[14] = -y0 + y1;  // col2
  M[3]  = -y0 + x1;  M[7]  =  y0 - y1;  M[11] = -y0 - x1;  M[15] =  y0 + y1;  // col3
#pragma unroll
  for (int k = 2; k < SCH; ++k) {
    float ppq = x[k], pmq = y[k];
#pragma unroll
    for (int j = 0; j < 4; ++j) {
      float r0 = M[0 * 4 + j], r1 = M[1 * 4 + j], r2 = M[2 * 4 + j], r3 = M[3 * 4 + j];
      M[0 * 4 + j] = fmaxf(r0 - ppq, r1 + ppq);
      M[2 * 4 + j] = fmaxf(r0 + ppq, r1 - ppq);
      M[1 * 4 + j] = fmaxf(r2 + pmq, r3 - pmq);
      M[3 * 4 + j] = fmaxf(r2 - pmq, r3 + pmq);
    }
  }
}

// one BCJR pass: 4 waves x 64 lanes x SCH steps; matrix scan + vector tails.
// Write indices pre-cached in registers (wi).
__device__ __forceinline__ void bcjr_pass(
    const float* ys, const float* La, float* dst, const int (&wi)[SCH],
    int finalLLR, const float (&q)[SCH], float (&fT)[4][16],
    int base, int lane, int w) {
  float x[SCH], y[SCH];
  {
    const float4* y4 = (const float4*)(ys + base);
    const float4* l4 = (const float4*)(La + base);
#pragma unroll
    for (int k = 0; k < SCH / 4; ++k) {
      float4 yv = y4[k], lv = l4[k];
      float p0 = yv.x + 0.5f * lv.x, p1 = yv.y + 0.5f * lv.y;
      float p2 = yv.z + 0.5f * lv.z, p3 = yv.w + 0.5f * lv.w;
      x[4 * k + 0] = p0 + q[4 * k + 0]; y[4 * k + 0] = p0 - q[4 * k + 0];
      x[4 * k + 1] = p1 + q[4 * k + 1]; y[4 * k + 1] = p1 - q[4 * k + 1];
      x[4 * k + 2] = p2 + q[4 * k + 2]; y[4 * k + 2] = p2 - q[4 * k + 2];
      x[4 * k + 3] = p3 + q[4 * k + 3]; y[4 * k + 3] = p3 - q[4 * k + 3];
    }
  }

  float P[16];
  buildM(x, y, P);
  float Q[16];
  cp16(Q, P);

  const int rl = lane & 15;
  const int row = lane >> 4;

  // ---- fwd inclusive prefix scan, full 64 lanes (6 DPP levels) ----
  {
    float T[16], N[16];
    shift16<0x111>(P, T); if (rl >= 1) { comb(P, T, N); cp16(P, N); }
    shift16<0x112>(P, T); if (rl >= 2) { comb(P, T, N); cp16(P, N); }
    shift16<0x114>(P, T); if (rl >= 4) { comb(P, T, N); cp16(P, N); }
    shift16<0x118>(P, T); if (rl >= 8) { comb(P, T, N); cp16(P, N); }
    shift16<0x142>(P, T); if (row & 1)  { comb(P, T, N); cp16(P, N); }  // bcast15
    shift16<0x143>(P, T); if (row >= 2) { comb(P, T, N); cp16(P, N); }  // bcast31
  }
  // ---- bwd inclusive suffix scan, IN-ROW ONLY (4 DPP levels) ----
  {
    float T[16], N[16];
    shift16<0x101>(Q, T); if (rl <= 14) { comb(T, Q, N); cp16(Q, N); }
    shift16<0x102>(Q, T); if (rl <= 13) { comb(T, Q, N); cp16(Q, N); }
    shift16<0x104>(Q, T); if (rl <= 11) { comb(T, Q, N); cp16(Q, N); }
    shift16<0x108>(Q, T); if (rl <= 7)  { comb(T, Q, N); cp16(Q, N); }
  }

  // ---- wave total (fwd total == bwd total) -> LDS ----
  if (lane == 63) cp16(fT[w], P);
  __syncthreads();

  // ---- forward vector chain: f = col0 of product of earlier waves' totals ----
  float f[4];
  if (w == 0) { f[0] = 0.f; f[1] = NEGV; f[2] = NEGV; f[3] = NEGV; }
  else {
    f[0] = fT[0][0]; f[1] = fT[0][4]; f[2] = fT[0][8]; f[3] = fT[0][12];
    if (w >= 2) matcol(fT[1], f);
    if (w >= 3) matcol(fT[2], f);
  }
  // ---- backward vector chain: u = colmax over later waves' totals ----
  float u[4];
  if (w == 3) { u[0] = u[1] = u[2] = u[3] = 0.f; }
  else {
    const float* T3 = fT[3];
#pragma unroll
    for (int j = 0; j < 4; ++j)
      u[j] = max4(T3[j], T3[4 + j], T3[8 + j], T3[12 + j]);
    if (w <= 1) rowmat(u, fT[2]);
    if (w == 0) rowmat(u, fT[1]);
  }
  // ---- extend u through later rows' totals within this wave ----
#pragma unroll
  for (int jj = 3; jj >= 1; --jj) {
    float T[16];
#pragma unroll
    for (int e = 0; e < 16; ++e) T[e] = __shfl(Q[e], jj << 4);  // lane jj*16 = row jj total
    if (row < jj) rowmat(u, T);
  }

  // ---- alpha at chunk start: v = P (x) f (inclusive), then shift by one lane ----
  float a[4];
  {
    float v0 = max4(P[0]  + f[0], P[1]  + f[1], P[2]  + f[2], P[3]  + f[3]);
    float v1 = max4(P[4]  + f[0], P[5]  + f[1], P[6]  + f[2], P[7]  + f[3]);
    float v2 = max4(P[8]  + f[0], P[9]  + f[1], P[10] + f[2], P[11] + f[3]);
    float v3 = max4(P[12] + f[0], P[13] + f[1], P[14] + f[2], P[15] + f[3]);
    float a0 = __shfl(v0, lane - 1), a1 = __shfl(v1, lane - 1);
    float a2 = __shfl(v2, lane - 1), a3 = __shfl(v3, lane - 1);
    if (lane == 0) { a0 = f[0]; a1 = f[1]; a2 = f[2]; a3 = f[3]; }
    a[0] = 0.f; a[1] = a1 - a0; a[2] = a2 - a0; a[3] = a3 - a0;
  }

  // ---- beta at chunk end: z = u (x) Q (inclusive suffix colmax), shift by one ----
  float b[4];
  {
    float z0 = max4(u[0] + Q[0], u[1] + Q[4], u[2] + Q[8],  u[3] + Q[12]);
    float z1 = max4(u[0] + Q[1], u[1] + Q[5], u[2] + Q[9],  u[3] + Q[13]);
    float z2 = max4(u[0] + Q[2], u[1] + Q[6], u[2] + Q[10], u[3] + Q[14]);
    float z3 = max4(u[0] + Q[3], u[1] + Q[7], u[2] + Q[11], u[3] + Q[15]);
    float b0 = __shfl(z0, lane + 1), b1 = __shfl(z1, lane + 1);
    float b2 = __shfl(z2, lane + 1), b3 = __shfl(z3, lane + 1);
    if (lane == 63) { b0 = u[0]; b1 = u[1]; b2 = u[2]; b3 = u[3]; }
    b[0] = 0.f; b[1] = b1 - b0; b[2] = b2 - b0; b[3] = b3 - b0;
  }

  // ---- local beta walk ----
  float bet[SCH][4];
  bet[SCH - 1][0] = b[0]; bet[SCH - 1][1] = b[1];
  bet[SCH - 1][2] = b[2]; bet[SCH - 1][3] = b[3];
#pragma unroll
  for (int k = SCH - 1; k >= 1; --k) {
    float ppq = x[k], pmq = y[k];
    float B0 = bet[k][0], B1 = bet[k][1], B2 = bet[k][2], B3 = bet[k][3];
    bet[k - 1][0] = fmaxf(B0 - ppq, B2 + ppq);
    bet[k - 1][1] = fmaxf(B2 - ppq, B0 + ppq);
    bet[k - 1][2] = fmaxf(B3 - pmq, B1 + pmq);
    bet[k - 1][3] = fmaxf(B1 - pmq, B3 + pmq);
  }

  // ---- alpha walk + LLR + scattered write (shared butterfly sums) ----
#pragma unroll
  for (int k = 0; k < SCH; ++k) {
    float ppq = x[k], pmq = y[k];
    float s0m = a[0] - ppq, s1p = a[1] + ppq, s0p = a[0] + ppq, s1m = a[1] - ppq;
    float s2p = a[2] + pmq, s3m = a[3] - pmq, s2m = a[2] - pmq, s3p = a[3] + pmq;
    float B0 = bet[k][0], B1 = bet[k][1], B2 = bet[k][2], B3 = bet[k][3];
    float m1 = max4(s0p + B2, s1p + B0, s2p + B1, s3p + B3);
    float m0 = max4(s0m + B0, s1m + B2, s2m + B3, s3m + B1);
    float llr = m1 - m0;
    // 2*p[k] == x[k] + y[k]
    float val = finalLLR ? llr : (llr - ppq - pmq);
    dst[wi[k]] = val;
    a[0] = fmaxf(s0m, s1p);
    a[2] = fmaxf(s0p, s1m);
    a[1] = fmaxf(s2p, s3m);
    a[3] = fmaxf(s2m, s3p);
  }
}

__device__ __forceinline__ unsigned fsm_compose(unsigned f, unsigned g) {
  unsigned nm = 0;
#pragma unroll
  for (int s = 0; s < 4; ++s) {
    unsigned gs = (g >> (8 * s)) & 3u;
    nm |= ((f >> (8 * gs)) & 0xFFu) << (8 * s);
  }
  return nm;
}

__global__ __launch_bounds__(TPR, 2) void turbo_kernel(
    const int* __restrict__ xg, const float* __restrict__ n1g,
    const float* __restrict__ n2g, const float* __restrict__ n3g,
    const int* __restrict__ pg, float* __restrict__ outg) {
  __shared__ SM sm;
  const int tid = threadIdx.x;
  const int lane = tid & 63, w = tid >> 6;
  const int base = tid * SCH;
  const size_t rb = (size_t)blockIdx.x * KLEN;

  // ---- load inputs ----
  int* Ai = (int*)sm.A;
  for (int i = tid; i < KLEN; i += TPR) {
    sm.perm[i] = (unsigned short)pg[i];
    int xv = xg[rb + i];
    Ai[i] = xv;
    sm.y1[i] = (2.f * xv - 1.f) + n1g[rb + i];
    sm.Lint[i] = 0.f;
  }
  float q2[SCH], q3[SCH];
  {
    size_t g0 = rb + (size_t)base;
#pragma unroll
    for (int k = 0; k < SCH; ++k) { q2[k] = n2g[g0 + k]; q3[k] = n3g[g0 + k]; }
  }
  __syncthreads();

  // ---- one-time: invp, interleaved systematic ----
  for (int i = tid; i < KLEN; i += TPR) {
    sm.invp[sm.perm[i]] = (unsigned short)i;
    sm.y1i[i] = sm.y1[sm.perm[i]];
  }

  // ---- RSC encode via FSM hierarchical scan ----
  unsigned ub1 = 0, ub2 = 0;
#pragma unroll
  for (int k = 0; k < SCH; ++k) {
    int t = base + k;
    ub1 |= (unsigned)(Ai[t] & 1) << k;
    ub2 |= (unsigned)(Ai[sm.perm[t]] & 1) << k;
  }
  unsigned m1 = 0x03020100u, m2 = 0x03020100u;
#pragma unroll
  for (int k = 0; k < SCH; ++k) {
    unsigned st1 = ((ub1 >> k) & 1) ? 0x03010002u : 0x01030200u;
    unsigned st2 = ((ub2 >> k) & 1) ? 0x03010002u : 0x01030200u;
    m1 = fsm_compose(st1, m1);
    m2 = fsm_compose(st2, m2);
  }
#pragma unroll
  for (int i = 0; i < 6; ++i) {
    const int d = 1 << i;
    unsigned t1 = __shfl_up(m1, d), t2 = __shfl_up(m2, d);
    if (lane >= d) { m1 = fsm_compose(m1, t1); m2 = fsm_compose(m2, t2); }
  }
  if (lane == 63) { sm.eT[w][0] = m1; sm.eT[w][1] = m2; }
  __syncthreads();
  {
    unsigned W1 = 0x03020100u, W2 = 0x03020100u;
    if (w >= 1) { W1 = sm.eT[0][0]; W2 = sm.eT[0][1]; }
    if (w >= 2) { W1 = fsm_compose(sm.eT[1][0], W1); W2 = fsm_compose(sm.eT[1][1], W2); }
    if (w >= 3) { W1 = fsm_compose(sm.eT[2][0], W1); W2 = fsm_compose(sm.eT[2][1], W2); }
    unsigned f1 = fsm_compose(m1, W1), f2 = fsm_compose(m2, W2);
    unsigned pf1 = __shfl_up(f1, 1), pf2 = __shfl_up(f2, 1);
    int s1 = (tid == 0) ? 0 : (lane == 0 ? (int)(W1 & 3u) : (int)(pf1 & 3u));
    int s2 = (tid == 0) ? 0 : (lane == 0 ? (int)(W2 & 3u) : (int)(pf2 & 3u));
#pragma unroll
    for (int k = 0; k < SCH; ++k) {
      { int u = (ub1 >> k) & 1, a = u ^ (s1 >> 1) ^ (s1 & 1), par = a ^ (s1 & 1);
        q2[k] += 2.f * par - 1.f; s1 = (a << 1) | (s1 >> 1); }
      { int u = (ub2 >> k) & 1, a = u ^ (s2 >> 1) ^ (s2 & 1), par = a ^ (s2 & 1);
        q3[k] += 2.f * par - 1.f; s2 = (a << 1) | (s2 >> 1); }
    }
  }
  __syncthreads();  // bits consumed; A becomes interleaved-La buffer

  // ---- cache scatter indices in registers (constant across iterations) ----
  int wi1[SCH], wi2[SCH];
#pragma unroll
  for (int k = 0; k < SCH; ++k) {
    wi1[k] = (int)sm.invp[base + k];
    wi2[k] = (int)sm.perm[base + k];
  }

  // ---- 6 turbo iterations ----
#pragma unroll 1
  for (int it = 0; it < 6; ++it) {
    bcjr_pass(sm.y1, sm.Lint, sm.A, wi1, 0, q2, sm.fT, base, lane, w);
    __syncthreads();
    const int fin = (it == 5);
    bcjr_pass(sm.y1i, sm.A, sm.Lint, wi2, fin, q3, sm.fT, base, lane, w);
    __syncthreads();
  }

  // ---- Lint holds deinterleaved L2; coalesced store ----
  for (int i = tid; i < KLEN; i += TPR) outg[rb + i] = sm.Lint[i];
}

extern "C" void kernel_launch(void* const* d_in, const int* in_sizes, int n_in,
                              void* d_out, int out_size, void* d_ws, size_t ws_size,
                              hipStream_t stream) {
  (void)n_in; (void)d_ws; (void)ws_size; (void)out_size;
  const int* x    = (const int*)d_in[0];
  const float* n1 = (const float*)d_in[1];
  const float* n2 = (const float*)d_in[2];
  const float* n3 = (const float*)d_in[3];
  const int* perm = (const int*)d_in[4];
  float* out = (float*)d_out;
  const int K = in_sizes[4];       // 2048
  const int B = in_sizes[0] / K;   // 512 rows, one per block
  turbo_kernel<<<B, TPR, 0, stream>>>(x, n1, n2, n3, perm, out);
}